// Round 12
// baseline (6272.464 us; speedup 1.0000x reference)
//
#include <hip/hip_runtime.h>

typedef unsigned short ushort_t;
typedef _Float16 half_t;
typedef __attribute__((ext_vector_type(8))) _Float16 half8;
typedef __attribute__((ext_vector_type(4))) float f32x4;

#define B_ 256
#define T_ 200
#define X_ 128
#define H_ 512

// swizzled weight offsets in d_ws (f16 elements)
#define OFF_WO1 0
#define OFF_WO2 57344
#define OFF_WU1 122880
#define OFF_WR1 251904
#define OFF_WN1 380928
#define OFF_WU2 509952
#define OFF_WR2 575488
#define OFF_WN2 641024
#define OFF_WT1 772096
#define OFF_WT2 886784
#define OFF_WT3 901120
#define SWZ_TOTAL 1032192
#define DTS_BYTE_OFF (SWZ_TOTAL * 2)

#define LOG2E 1.4426950408889634f

struct Args {
  const float *x_data, *x_time;
  const float *Wu1, *bu1, *Wu2, *bu2;
  const float *Wr1, *br1, *Wr2, *br2;
  const float *Wn1, *bn1, *Wn2, *bn2;
  const float *Wo1, *bo1, *Wo2, *bo2;
  const float *Wt1, *bt1, *Wt2, *bt2, *Wt3, *bt3;
  float* out;      // f32 output: mu[256*512] then sigma[256*512]
  half_t* wsw;     // swizzled weights (f16)
  float* dts;      // 200 per-step dt values
};

// hw-instruction activations: v_exp_f32 (exp2) + v_rcp_f32. abs err ~1e-5 —
// far below the f16 operand rounding already proven output-invisible (r1-3).
__device__ __forceinline__ float fast_sigm(float x) {
  return __builtin_amdgcn_rcpf(1.0f + __builtin_amdgcn_exp2f(-LOG2E * x));
}
__device__ __forceinline__ float fast_tanh(float x) {
  return 1.0f - 2.0f * __builtin_amdgcn_rcpf(1.0f + __builtin_amdgcn_exp2f((2.0f * LOG2E) * x));
}

// One 16x16 output tile, K = KB*32. A from LDS (f16, row-major, stride astride),
// B from pre-swizzled global (fragment-major: 512 elems per k-block).
// Layouts (HW-verified; orchestration cross-validated bit-identical vs f32-VALU
// reference in rounds 1-3):
//   A[m = lane&15][k = (lane>>4)*8 + j]
//   B[k = (lane>>4)*8 + j][n = lane&15]
//   C/D: col = lane&15, row = (lane>>4)*4 + reg
template <int KB>
__device__ __forceinline__ f32x4 gemm_tile(const half_t* __restrict__ wtile,
                                           const half_t* __restrict__ abase,
                                           int astride, int lane, f32x4 acc) {
  const half_t* ap = abase + (lane & 15) * astride + 8 * (lane >> 4);
  const half_t* wp = wtile + lane * 8;
#pragma unroll
  for (int kb = 0; kb < KB; ++kb) {
    half8 af = *(const half8*)(ap + kb * 32);
    half8 bf = *(const half8*)(wp + kb * 512);
    acc = __builtin_amdgcn_mfma_f32_16x16x32_f16(af, bf, acc, 0, 0, 0);
  }
  return acc;
}

// KB=4 (K=128) stage with NT tiles sharing the same A operand: ds_read A once,
// independent acc chains across tiles for ILP. Tile s sits at
// wbase + (wave + s*16)*4*512 (matches the prior per-tile indexing exactly).
template <int NT>
__device__ __forceinline__ void gemm4_multi(const half_t* __restrict__ wbase,
                                            int wave,
                                            const half_t* __restrict__ abase,
                                            int astride, int lane, f32x4* accs) {
  const half_t* ap = abase + (lane & 15) * astride + 8 * (lane >> 4);
  half8 af[4];
#pragma unroll
  for (int j = 0; j < 4; ++j) af[j] = *(const half8*)(ap + j * 32);
#pragma unroll
  for (int s = 0; s < NT; ++s) {
    const half_t* wp = wbase + (size_t)(wave + s * 16) * 4 * 512 + lane * 8;
    f32x4 acc = {0.f, 0.f, 0.f, 0.f};
#pragma unroll
    for (int j = 0; j < 4; ++j) {
      half8 bf = *(const half8*)(wp + j * 512);
      acc = __builtin_amdgcn_mfma_f32_16x16x32_f16(af[j], bf, acc, 0, 0, 0);
    }
    accs[s] = acc;
  }
}

// Pre-swizzle f32 weights into f16 MFMA B-fragment layout, K padded to mult of
// 32 (zeros), N padded to mult of 16 (zeros).
__global__ void swz_kernel(Args a) {
  struct WT { const float* src; int off; int KB; int Kr; int Nr; };
  const WT tbl[11] = {
      {a.Wo1, OFF_WO1, 16, 512, 100},  {a.Wo2, OFF_WO2, 4, 100, 512},
      {a.Wu1, OFF_WU1, 36, 1152, 100}, {a.Wr1, OFF_WR1, 36, 1152, 100},
      {a.Wn1, OFF_WN1, 36, 1152, 100}, {a.Wu2, OFF_WU2, 4, 100, 512},
      {a.Wr2, OFF_WR2, 4, 100, 512},   {a.Wn2, OFF_WN2, 4, 100, 1024},
      {a.Wt1, OFF_WT1, 32, 1024, 100}, {a.Wt2, OFF_WT2, 4, 100, 100},
      {a.Wt3, OFF_WT3, 4, 100, 1024}};
  const int ends[11] = {OFF_WO2, OFF_WU1, OFF_WR1, OFF_WN1, OFF_WU2, OFF_WR2,
                        OFF_WN2, OFF_WT1, OFF_WT2, OFF_WT3, SWZ_TOTAL};
  int gid = blockIdx.x * blockDim.x + threadIdx.x;
  int e8 = gid * 8;
  if (e8 >= SWZ_TOTAL) return;
  int w = 0;
  while (e8 >= ends[w]) ++w;
  const WT T = tbl[w];
  int local = e8 - T.off;
  int lane = (local >> 3) & 63;
  int blk = local >> 9;  // nt*KB + kb
  int kb = blk % T.KB, nt = blk / T.KB;
  int n = nt * 16 + (lane & 15);
  int k0 = kb * 32 + 8 * (lane >> 4);
#pragma unroll
  for (int j = 0; j < 8; ++j) {
    int k = k0 + j;
    float v = (k < T.Kr && n < T.Nr) ? T.src[k * T.Nr + n] : 0.0f;
    a.wsw[e8 + j] = (half_t)v;
  }
}

__global__ void dts_kernel(Args a) {
  int t = threadIdx.x;
  if (t >= T_) return;
  float v;
  if (t == 0)      v = -0.01f;
  else if (t == 1) v = a.x_time[T_ - 1] - a.x_time[0];
  else             v = a.x_time[t - 2] - a.x_time[t - 1];
  a.dts[t] = v;
}

// Persistent ODE-GRU scan: 16 blocks x 1024 threads; block b owns batch rows
// [16b,16b+16). h/hs state in registers at this thread's C-fragment positions:
//   hreg[s*4+i]  = h [m=g*4+i][n=(wave+s*16)*16+lm]   (s=0,1)
__global__ __launch_bounds__(1024) void odegru_kernel(Args a) {
  // yc stride 1160 f16 (=580 dw == 4 mod 32 -> 2-way-free LDS banks)
  __shared__ __align__(16) half_t yc[16 * 1160];   // [h_ode | hs | x] then c
  __shared__ __align__(16) half_t tg[16 * 136];    // K-padded t-buffers
  __shared__ __align__(16) half_t tu[16 * 136];
  __shared__ __align__(16) half_t tr[16 * 136];
  __shared__ __align__(16) half_t tn[16 * 136];
  __shared__ float dts_s[T_];

  const int tid = threadIdx.x;
  const int wave = tid >> 6;
  const int lane = tid & 63;
  const int lm = lane & 15;   // A-frag row / C-frag col
  const int g = lane >> 4;    // k-group / C-row group
  const int row0 = blockIdx.x * 16;

  for (int i = tid; i < 16 * 136; i += 1024) {
    tg[i] = (half_t)0.f; tu[i] = (half_t)0.f; tr[i] = (half_t)0.f; tn[i] = (half_t)0.f;
  }
  if (tid < T_) dts_s[tid] = a.dts[tid];

  float hreg[8], hsreg[8];
#pragma unroll
  for (int i = 0; i < 8; ++i) { hreg[i] = 0.f; hsreg[i] = 0.f; }
  float ureg[8];  // u gate: producer wave == consumer wave

  // x prefetch: thread covers elements tid and tid+1024 of the 16x128 slab
  const int xm0 = tid >> 7, xk0 = tid & 127;
  const int xm1 = (tid + 1024) >> 7, xk1 = (tid + 1024) & 127;
  float xpre0 = a.x_data[((long)(row0 + xm0) * T_ + 0) * X_ + xk0];
  float xpre1 = a.x_data[((long)(row0 + xm1) * T_ + 0) * X_ + xk1];
  __syncthreads();

  for (int t = 0; t < T_; ++t) {
    const float dt = dts_s[t];
    // ---- S0: yc = [f16(h) | f16(hs) | f16(x_t)]; issue x_{t+1} prefetch ----
#pragma unroll
    for (int s = 0; s < 2; ++s) {
      int n = (wave + s * 16) * 16 + lm;
#pragma unroll
      for (int i = 0; i < 4; ++i) {
        int m = g * 4 + i;
        yc[m * 1160 + n]       = (half_t)hreg[s * 4 + i];
        yc[m * 1160 + 512 + n] = (half_t)hsreg[s * 4 + i];
      }
    }
    yc[xm0 * 1160 + 1024 + xk0] = (half_t)xpre0;
    yc[xm1 * 1160 + 1024 + xk1] = (half_t)xpre1;
    if (t + 1 < T_) {  // loads in flight for the whole step
      xpre0 = a.x_data[((long)(row0 + xm0) * T_ + (t + 1)) * X_ + xk0];
      xpre1 = a.x_data[((long)(row0 + xm1) * T_ + (t + 1)) * X_ + xk1];
    }
    __syncthreads();
    // ---- S1: tg = tanh(h @ Wo1 + bo1) ----
    for (int nt = wave; nt < 7; nt += 16) {
      f32x4 acc = {0.f, 0.f, 0.f, 0.f};
      acc = gemm_tile<16>(a.wsw + OFF_WO1 + nt * 16 * 512, yc, 1160, lane, acc);
      int n = nt * 16 + lm;
      if (n < 100) {
        float bias = a.bo1[n];
#pragma unroll
        for (int i = 0; i < 4; ++i)
          tg[(g * 4 + i) * 136 + n] = (half_t)fast_tanh(acc[i] + bias);
      }
    }
    __syncthreads();
    // ---- S2: h_ode = h + dt*(tg @ Wo2 + bo2) ----
    {
      f32x4 accs[2];
      gemm4_multi<2>(a.wsw + OFF_WO2, wave, tg, 136, lane, accs);
#pragma unroll
      for (int s = 0; s < 2; ++s) {
        int n = (wave + s * 16) * 16 + lm;
        float bias = a.bo2[n];
#pragma unroll
        for (int i = 0; i < 4; ++i) {
          int m = g * 4 + i;
          float h_ode = hreg[s * 4 + i] + dt * (accs[s][i] + bias);
          hreg[s * 4 + i] = h_ode;
          yc[m * 1160 + n] = (half_t)h_ode;
        }
      }
    }
    __syncthreads();
    // ---- S3: tu = tanh(yc@Wu1+bu1), tr = tanh(yc@Wr1+br1) (merged, 14 tiles) ----
    for (int nt = wave; nt < 14; nt += 16) {
      bool isU = nt < 7;
      int nt7 = isU ? nt : nt - 7;
      f32x4 acc = {0.f, 0.f, 0.f, 0.f};
      acc = gemm_tile<36>(a.wsw + (isU ? OFF_WU1 : OFF_WR1) + nt7 * 36 * 512, yc, 1160, lane, acc);
      int n = nt7 * 16 + lm;
      if (n < 100) {
        float bias = (isU ? a.bu1 : a.br1)[n];
        half_t* dst = isU ? tu : tr;
#pragma unroll
        for (int i = 0; i < 4; ++i)
          dst[(g * 4 + i) * 136 + n] = (half_t)fast_tanh(acc[i] + bias);
      }
    }
    __syncthreads();
    // ---- S4: u -> ureg ; r -> fused c-build into yc ----
    {
      f32x4 ua[2], ra[2];
      gemm4_multi<2>(a.wsw + OFF_WU2, wave, tu, 136, lane, ua);
      gemm4_multi<2>(a.wsw + OFF_WR2, wave, tr, 136, lane, ra);
#pragma unroll
      for (int s = 0; s < 2; ++s) {
        int n = (wave + s * 16) * 16 + lm;
        float bu = a.bu2[n], br = a.br2[n];
#pragma unroll
        for (int i = 0; i < 4; ++i) {
          int m = g * 4 + i;
          ureg[s * 4 + i] = fast_sigm(ua[s][i] + bu);
          float r = fast_sigm(ra[s][i] + br);
          yc[m * 1160 + n]       = (half_t)(hreg[s * 4 + i] * r);
          yc[m * 1160 + 512 + n] = (half_t)(hsreg[s * 4 + i] * r);
        }
      }
    }
    __syncthreads();
    // ---- S5: tn = tanh(c @ Wn1 + bn1) ----
    for (int nt = wave; nt < 7; nt += 16) {
      f32x4 acc = {0.f, 0.f, 0.f, 0.f};
      acc = gemm_tile<36>(a.wsw + OFF_WN1 + nt * 36 * 512, yc, 1160, lane, acc);
      int n = nt * 16 + lm;
      if (n < 100) {
        float bias = a.bn1[n];
#pragma unroll
        for (int i = 0; i < 4; ++i)
          tn[(g * 4 + i) * 136 + n] = (half_t)fast_tanh(acc[i] + bias);
      }
    }
    __syncthreads();
    // ---- S6: ns = tn @ Wn2 + bn2; gated state update in registers ----
    {
      f32x4 accs[4];
      gemm4_multi<4>(a.wsw + OFF_WN2, wave, tn, 136, lane, accs);
#pragma unroll
      for (int s = 0; s < 4; ++s) {
        int n = (wave + s * 16) * 16 + lm;
        float bias = a.bn2[n];
        if (s < 2) {  // m-part -> h update
#pragma unroll
          for (int i = 0; i < 4; ++i) {
            float u = ureg[s * 4 + i];
            float mval = accs[s][i] + bias;
            hreg[s * 4 + i] = (1.0f - u) * mval + u * hreg[s * 4 + i];
          }
        } else {      // s-part -> hs update (same n-tile as ureg[s-2])
#pragma unroll
          for (int i = 0; i < 4; ++i) {
            float u = ureg[(s - 2) * 4 + i];
            float sval = fabsf(accs[s][i] + bias);
            hsreg[(s - 2) * 4 + i] = (1.0f - u) * sval + u * hsreg[(s - 2) * 4 + i];
          }
        }
      }
    }
    __syncthreads();
  }

  // ---- Final decoder ----
#pragma unroll
  for (int s = 0; s < 2; ++s) {
    int n = (wave + s * 16) * 16 + lm;
#pragma unroll
    for (int i = 0; i < 4; ++i) {
      int m = g * 4 + i;
      yc[m * 1160 + n]       = (half_t)hreg[s * 4 + i];
      yc[m * 1160 + 512 + n] = (half_t)hsreg[s * 4 + i];
    }
  }
  __syncthreads();
  for (int nt = wave; nt < 7; nt += 16) {  // z1 = tanh(hcat@Wt1+bt1)
    f32x4 acc = {0.f, 0.f, 0.f, 0.f};
    acc = gemm_tile<32>(a.wsw + OFF_WT1 + nt * 32 * 512, yc, 1160, lane, acc);
    int n = nt * 16 + lm;
    if (n < 100) {
      float bias = a.bt1[n];
#pragma unroll
      for (int i = 0; i < 4; ++i)
        tu[(g * 4 + i) * 136 + n] = (half_t)fast_tanh(acc[i] + bias);
    }
  }
  __syncthreads();
  for (int nt = wave; nt < 7; nt += 16) {  // z2 = tanh(z1@Wt2+bt2)
    f32x4 acc = {0.f, 0.f, 0.f, 0.f};
    acc = gemm_tile<4>(a.wsw + OFF_WT2 + nt * 4 * 512, tu, 136, lane, acc);
    int n = nt * 16 + lm;
    if (n < 100) {
      float bias = a.bt2[n];
#pragma unroll
      for (int i = 0; i < 4; ++i)
        tr[(g * 4 + i) * 136 + n] = (half_t)fast_tanh(acc[i] + bias);
    }
  }
  __syncthreads();
  {  // z3 = z2@Wt3+bt3 -> mu | sigma (f32 out)
    f32x4 accs[4];
    gemm4_multi<4>(a.wsw + OFF_WT3, wave, tr, 136, lane, accs);
#pragma unroll
    for (int s = 0; s < 4; ++s) {
      int n = (wave + s * 16) * 16 + lm;
      float bias = a.bt3[n];
#pragma unroll
      for (int i = 0; i < 4; ++i) {
        int grow = row0 + g * 4 + i;
        float val = accs[s][i] + bias;
        if (n < 512)
          a.out[(size_t)grow * 512 + n] = val;
        else
          a.out[(size_t)(B_ * 512) + (size_t)grow * 512 + (n - 512)] = fabsf(val);
      }
    }
  }
}

extern "C" void kernel_launch(void* const* d_in, const int* in_sizes, int n_in,
                              void* d_out, int out_size, void* d_ws, size_t ws_size,
                              hipStream_t stream) {
  Args a;
  a.x_data = (const float*)d_in[0];
  a.x_time = (const float*)d_in[1];
  a.Wu1 = (const float*)d_in[2];  a.bu1 = (const float*)d_in[3];
  a.Wu2 = (const float*)d_in[4];  a.bu2 = (const float*)d_in[5];
  a.Wr1 = (const float*)d_in[6];  a.br1 = (const float*)d_in[7];
  a.Wr2 = (const float*)d_in[8];  a.br2 = (const float*)d_in[9];
  a.Wn1 = (const float*)d_in[10]; a.bn1 = (const float*)d_in[11];
  a.Wn2 = (const float*)d_in[12]; a.bn2 = (const float*)d_in[13];
  a.Wo1 = (const float*)d_in[14]; a.bo1 = (const float*)d_in[15];
  a.Wo2 = (const float*)d_in[16]; a.bo2 = (const float*)d_in[17];
  a.Wt1 = (const float*)d_in[18]; a.bt1 = (const float*)d_in[19];
  a.Wt2 = (const float*)d_in[20]; a.bt2 = (const float*)d_in[21];
  a.Wt3 = (const float*)d_in[22]; a.bt3 = (const float*)d_in[23];
  a.out = (float*)d_out;
  a.wsw = (half_t*)d_ws;
  a.dts = (float*)((char*)d_ws + DTS_BYTE_OFF);

  swz_kernel<<<dim3(504), dim3(256), 0, stream>>>(a);
  dts_kernel<<<dim3(1), dim3(256), 0, stream>>>(a);
  odegru_kernel<<<dim3(16), dim3(1024), 0, stream>>>(a);
}

// Round 13
// 3670.467 us; speedup vs baseline: 1.7089x; 1.7089x over previous
//
#include <hip/hip_runtime.h>

typedef unsigned short ushort_t;
typedef _Float16 half_t;
typedef __attribute__((ext_vector_type(8))) _Float16 half8;
typedef __attribute__((ext_vector_type(4))) float f32x4;

#define B_ 256
#define T_ 200
#define X_ 128
#define H_ 512

// swizzled weight offsets in d_ws (f16 elements)
#define OFF_WO1 0
#define OFF_WO2 57344
#define OFF_WU1 122880
#define OFF_WR1 251904
#define OFF_WN1 380928
#define OFF_WU2 509952
#define OFF_WR2 575488
#define OFF_WN2 641024
#define OFF_WT1 772096
#define OFF_WT2 886784
#define OFF_WT3 901120
#define SWZ_TOTAL 1032192
#define DTS_BYTE_OFF (SWZ_TOTAL * 2)

#define LOG2E 1.4426950408889634f

struct Args {
  const float *x_data, *x_time;
  const float *Wu1, *bu1, *Wu2, *bu2;
  const float *Wr1, *br1, *Wr2, *br2;
  const float *Wn1, *bn1, *Wn2, *bn2;
  const float *Wo1, *bo1, *Wo2, *bo2;
  const float *Wt1, *bt1, *Wt2, *bt2, *Wt3, *bt3;
  float* out;      // f32 output: mu[256*512] then sigma[256*512]
  half_t* wsw;     // swizzled weights (f16)
  float* dts;      // 200 per-step dt values
};

// hw-instruction activations: v_exp_f32 + v_rcp_f32 (~5 instr vs ~25 libm).
// Validated round 12: VALUBusy -70%, absmax unchanged (f16 path dominates).
__device__ __forceinline__ float fast_sigm(float x) {
  return __builtin_amdgcn_rcpf(1.0f + __builtin_amdgcn_exp2f(-LOG2E * x));
}
__device__ __forceinline__ float fast_tanh(float x) {
  return 1.0f - 2.0f * __builtin_amdgcn_rcpf(1.0f + __builtin_amdgcn_exp2f((2.0f * LOG2E) * x));
}

// One 16x16 output tile, K = KB*32. A from LDS (f16, row-major, stride astride),
// B from pre-swizzled global (fragment-major: 512 elems per k-block).
// NOTE: keep "#pragma unroll 4" — full unroll at KB=36 blows the 64-VGPR
// budget the compiler pins for 16-wave blocks and spills to scratch
// (round 12: WRITE_SIZE 2.9->14.4 MB, dur +58%).
template <int KB>
__device__ __forceinline__ f32x4 gemm_tile(const half_t* __restrict__ wtile,
                                           const half_t* __restrict__ abase,
                                           int astride, int lane, f32x4 acc) {
  const half_t* ap = abase + (lane & 15) * astride + 8 * (lane >> 4);
  const half_t* wp = wtile + lane * 8;
#pragma unroll 4
  for (int kb = 0; kb < KB; ++kb) {
    half8 af = *(const half8*)(ap + kb * 32);
    half8 bf = *(const half8*)(wp + kb * 512);
    acc = __builtin_amdgcn_mfma_f32_16x16x32_f16(af, bf, acc, 0, 0, 0);
  }
  return acc;
}

// Pre-swizzle f32 weights into f16 MFMA B-fragment layout, K padded to mult of
// 32 (zeros), N padded to mult of 16 (zeros).
__global__ void swz_kernel(Args a) {
  struct WT { const float* src; int off; int KB; int Kr; int Nr; };
  const WT tbl[11] = {
      {a.Wo1, OFF_WO1, 16, 512, 100},  {a.Wo2, OFF_WO2, 4, 100, 512},
      {a.Wu1, OFF_WU1, 36, 1152, 100}, {a.Wr1, OFF_WR1, 36, 1152, 100},
      {a.Wn1, OFF_WN1, 36, 1152, 100}, {a.Wu2, OFF_WU2, 4, 100, 512},
      {a.Wr2, OFF_WR2, 4, 100, 512},   {a.Wn2, OFF_WN2, 4, 100, 1024},
      {a.Wt1, OFF_WT1, 32, 1024, 100}, {a.Wt2, OFF_WT2, 4, 100, 100},
      {a.Wt3, OFF_WT3, 4, 100, 1024}};
  const int ends[11] = {OFF_WO2, OFF_WU1, OFF_WR1, OFF_WN1, OFF_WU2, OFF_WR2,
                        OFF_WN2, OFF_WT1, OFF_WT2, OFF_WT3, SWZ_TOTAL};
  int gid = blockIdx.x * blockDim.x + threadIdx.x;
  int e8 = gid * 8;
  if (e8 >= SWZ_TOTAL) return;
  int w = 0;
  while (e8 >= ends[w]) ++w;
  const WT T = tbl[w];
  int local = e8 - T.off;
  int lane = (local >> 3) & 63;
  int blk = local >> 9;  // nt*KB + kb
  int kb = blk % T.KB, nt = blk / T.KB;
  int n = nt * 16 + (lane & 15);
  int k0 = kb * 32 + 8 * (lane >> 4);
#pragma unroll
  for (int j = 0; j < 8; ++j) {
    int k = k0 + j;
    float v = (k < T.Kr && n < T.Nr) ? T.src[k * T.Nr + n] : 0.0f;
    a.wsw[e8 + j] = (half_t)v;
  }
}

__global__ void dts_kernel(Args a) {
  int t = threadIdx.x;
  if (t >= T_) return;
  float v;
  if (t == 0)      v = -0.01f;
  else if (t == 1) v = a.x_time[T_ - 1] - a.x_time[0];
  else             v = a.x_time[t - 2] - a.x_time[t - 1];
  a.dts[t] = v;
}

// Persistent ODE-GRU scan: 16 blocks x 1024 threads; block b owns batch rows
// [16b,16b+16). h/hs state in registers at this thread's C-fragment positions:
//   hreg[s*4+i]  = h [m=g*4+i][n=(wave+s*16)*16+lm]   (s=0,1)
__global__ __launch_bounds__(1024) void odegru_kernel(Args a) {
  // yc stride 1160 f16 (=580 dw == 4 mod 32 -> 2-way-free LDS banks)
  __shared__ __align__(16) half_t yc[16 * 1160];   // [h_ode | hs | x] then c
  __shared__ __align__(16) half_t tg[16 * 136];    // K-padded t-buffers
  __shared__ __align__(16) half_t tu[16 * 136];
  __shared__ __align__(16) half_t tr[16 * 136];
  __shared__ __align__(16) half_t tn[16 * 136];
  __shared__ float dts_s[T_];

  const int tid = threadIdx.x;
  const int wave = tid >> 6;
  const int lane = tid & 63;
  const int lm = lane & 15;   // A-frag row / C-frag col
  const int g = lane >> 4;    // k-group / C-row group
  const int row0 = blockIdx.x * 16;

  for (int i = tid; i < 16 * 136; i += 1024) {
    tg[i] = (half_t)0.f; tu[i] = (half_t)0.f; tr[i] = (half_t)0.f; tn[i] = (half_t)0.f;
  }
  if (tid < T_) dts_s[tid] = a.dts[tid];

  float hreg[8], hsreg[8];
#pragma unroll
  for (int i = 0; i < 8; ++i) { hreg[i] = 0.f; hsreg[i] = 0.f; }
  float ureg[8];  // u gate: producer wave == consumer wave
  __syncthreads();

  for (int t = 0; t < T_; ++t) {
    const float dt = dts_s[t];
    // ---- S0: yc = [f16(h) | f16(hs) | f16(x_t)] ----
#pragma unroll
    for (int s = 0; s < 2; ++s) {
      int n = (wave + s * 16) * 16 + lm;
#pragma unroll
      for (int i = 0; i < 4; ++i) {
        int m = g * 4 + i;
        yc[m * 1160 + n]       = (half_t)hreg[s * 4 + i];
        yc[m * 1160 + 512 + n] = (half_t)hsreg[s * 4 + i];
      }
    }
    for (int i = tid; i < 16 * 128; i += 1024) {
      int m = i >> 7, xk = i & 127;
      yc[m * 1160 + 1024 + xk] = (half_t)a.x_data[((long)(row0 + m) * T_ + t) * X_ + xk];
    }
    __syncthreads();
    // ---- S1: tg = tanh(h @ Wo1 + bo1) ----
    for (int nt = wave; nt < 7; nt += 16) {
      f32x4 acc = {0.f, 0.f, 0.f, 0.f};
      acc = gemm_tile<16>(a.wsw + OFF_WO1 + nt * 16 * 512, yc, 1160, lane, acc);
      int n = nt * 16 + lm;
      if (n < 100) {
        float bias = a.bo1[n];
#pragma unroll
        for (int i = 0; i < 4; ++i)
          tg[(g * 4 + i) * 136 + n] = (half_t)fast_tanh(acc[i] + bias);
      }
    }
    __syncthreads();
    // ---- S2: h_ode = h + dt*(tg @ Wo2 + bo2); hreg := h_ode; yc := f16(h_ode) ----
#pragma unroll
    for (int s = 0; s < 2; ++s) {
      int nt = wave + s * 16;
      f32x4 acc = {0.f, 0.f, 0.f, 0.f};
      acc = gemm_tile<4>(a.wsw + OFF_WO2 + nt * 4 * 512, tg, 136, lane, acc);
      int n = nt * 16 + lm;
      float bias = a.bo2[n];
#pragma unroll
      for (int i = 0; i < 4; ++i) {
        int m = g * 4 + i;
        float h_ode = hreg[s * 4 + i] + dt * (acc[i] + bias);
        hreg[s * 4 + i] = h_ode;
        yc[m * 1160 + n] = (half_t)h_ode;
      }
    }
    __syncthreads();
    // ---- S3: tu = tanh(yc@Wu1+bu1), tr = tanh(yc@Wr1+br1) (merged, 14 tiles) ----
    for (int nt = wave; nt < 14; nt += 16) {
      bool isU = nt < 7;
      int nt7 = isU ? nt : nt - 7;
      f32x4 acc = {0.f, 0.f, 0.f, 0.f};
      acc = gemm_tile<36>(a.wsw + (isU ? OFF_WU1 : OFF_WR1) + nt7 * 36 * 512, yc, 1160, lane, acc);
      int n = nt7 * 16 + lm;
      if (n < 100) {
        float bias = (isU ? a.bu1 : a.br1)[n];
        half_t* dst = isU ? tu : tr;
#pragma unroll
        for (int i = 0; i < 4; ++i)
          dst[(g * 4 + i) * 136 + n] = (half_t)fast_tanh(acc[i] + bias);
      }
    }
    __syncthreads();
    // ---- S4: u -> ureg ; r -> fused c-build into yc ----
#pragma unroll
    for (int s = 0; s < 2; ++s) {
      int nt = wave + s * 16;
      f32x4 acc = {0.f, 0.f, 0.f, 0.f};
      acc = gemm_tile<4>(a.wsw + OFF_WU2 + nt * 4 * 512, tu, 136, lane, acc);
      int n = nt * 16 + lm;
      float bias = a.bu2[n];
#pragma unroll
      for (int i = 0; i < 4; ++i) ureg[s * 4 + i] = fast_sigm(acc[i] + bias);
    }
#pragma unroll
    for (int s = 0; s < 2; ++s) {
      int nt = wave + s * 16;
      f32x4 acc = {0.f, 0.f, 0.f, 0.f};
      acc = gemm_tile<4>(a.wsw + OFF_WR2 + nt * 4 * 512, tr, 136, lane, acc);
      int n = nt * 16 + lm;
      float bias = a.br2[n];
#pragma unroll
      for (int i = 0; i < 4; ++i) {
        int m = g * 4 + i;
        float r = fast_sigm(acc[i] + bias);
        yc[m * 1160 + n]       = (half_t)(hreg[s * 4 + i] * r);
        yc[m * 1160 + 512 + n] = (half_t)(hsreg[s * 4 + i] * r);
      }
    }
    __syncthreads();
    // ---- S5: tn = tanh(c @ Wn1 + bn1) ----
    for (int nt = wave; nt < 7; nt += 16) {
      f32x4 acc = {0.f, 0.f, 0.f, 0.f};
      acc = gemm_tile<36>(a.wsw + OFF_WN1 + nt * 36 * 512, yc, 1160, lane, acc);
      int n = nt * 16 + lm;
      if (n < 100) {
        float bias = a.bn1[n];
#pragma unroll
        for (int i = 0; i < 4; ++i)
          tn[(g * 4 + i) * 136 + n] = (half_t)fast_tanh(acc[i] + bias);
      }
    }
    __syncthreads();
    // ---- S6: ns = tn @ Wn2 + bn2; gated state update in registers ----
#pragma unroll
    for (int s = 0; s < 4; ++s) {
      int nt = wave + s * 16;
      f32x4 acc = {0.f, 0.f, 0.f, 0.f};
      acc = gemm_tile<4>(a.wsw + OFF_WN2 + nt * 4 * 512, tn, 136, lane, acc);
      int n = nt * 16 + lm;
      float bias = a.bn2[n];
      if (s < 2) {  // m-part -> h update
#pragma unroll
        for (int i = 0; i < 4; ++i) {
          float u = ureg[s * 4 + i];
          float mval = acc[i] + bias;
          hreg[s * 4 + i] = (1.0f - u) * mval + u * hreg[s * 4 + i];
        }
      } else {      // s-part -> hs update (same n-tile as ureg[s-2])
#pragma unroll
        for (int i = 0; i < 4; ++i) {
          float u = ureg[(s - 2) * 4 + i];
          float sval = fabsf(acc[i] + bias);
          hsreg[(s - 2) * 4 + i] = (1.0f - u) * sval + u * hsreg[(s - 2) * 4 + i];
        }
      }
    }
    __syncthreads();
  }

  // ---- Final decoder ----
#pragma unroll
  for (int s = 0; s < 2; ++s) {
    int n = (wave + s * 16) * 16 + lm;
#pragma unroll
    for (int i = 0; i < 4; ++i) {
      int m = g * 4 + i;
      yc[m * 1160 + n]       = (half_t)hreg[s * 4 + i];
      yc[m * 1160 + 512 + n] = (half_t)hsreg[s * 4 + i];
    }
  }
  __syncthreads();
  for (int nt = wave; nt < 7; nt += 16) {  // z1 = tanh(hcat@Wt1+bt1)
    f32x4 acc = {0.f, 0.f, 0.f, 0.f};
    acc = gemm_tile<32>(a.wsw + OFF_WT1 + nt * 32 * 512, yc, 1160, lane, acc);
    int n = nt * 16 + lm;
    if (n < 100) {
      float bias = a.bt1[n];
#pragma unroll
      for (int i = 0; i < 4; ++i)
        tu[(g * 4 + i) * 136 + n] = (half_t)fast_tanh(acc[i] + bias);
    }
  }
  __syncthreads();
  for (int nt = wave; nt < 7; nt += 16) {  // z2 = tanh(z1@Wt2+bt2)
    f32x4 acc = {0.f, 0.f, 0.f, 0.f};
    acc = gemm_tile<4>(a.wsw + OFF_WT2 + nt * 4 * 512, tu, 136, lane, acc);
    int n = nt * 16 + lm;
    if (n < 100) {
      float bias = a.bt2[n];
#pragma unroll
      for (int i = 0; i < 4; ++i)
        tr[(g * 4 + i) * 136 + n] = (half_t)fast_tanh(acc[i] + bias);
    }
  }
  __syncthreads();
#pragma unroll
  for (int s = 0; s < 4; ++s) {  // z3 = z2@Wt3+bt3 -> mu | sigma (f32 out)
    int nt = wave + s * 16;
    f32x4 acc = {0.f, 0.f, 0.f, 0.f};
    acc = gemm_tile<4>(a.wsw + OFF_WT3 + nt * 4 * 512, tr, 136, lane, acc);
    int n = nt * 16 + lm;
    float bias = a.bt3[n];
#pragma unroll
    for (int i = 0; i < 4; ++i) {
      int grow = row0 + g * 4 + i;
      float val = acc[i] + bias;
      if (n < 512)
        a.out[(size_t)grow * 512 + n] = val;
      else
        a.out[(size_t)(B_ * 512) + (size_t)grow * 512 + (n - 512)] = fabsf(val);
    }
  }
}

extern "C" void kernel_launch(void* const* d_in, const int* in_sizes, int n_in,
                              void* d_out, int out_size, void* d_ws, size_t ws_size,
                              hipStream_t stream) {
  Args a;
  a.x_data = (const float*)d_in[0];
  a.x_time = (const float*)d_in[1];
  a.Wu1 = (const float*)d_in[2];  a.bu1 = (const float*)d_in[3];
  a.Wu2 = (const float*)d_in[4];  a.bu2 = (const float*)d_in[5];
  a.Wr1 = (const float*)d_in[6];  a.br1 = (const float*)d_in[7];
  a.Wr2 = (const float*)d_in[8];  a.br2 = (const float*)d_in[9];
  a.Wn1 = (const float*)d_in[10]; a.bn1 = (const float*)d_in[11];
  a.Wn2 = (const float*)d_in[12]; a.bn2 = (const float*)d_in[13];
  a.Wo1 = (const float*)d_in[14]; a.bo1 = (const float*)d_in[15];
  a.Wo2 = (const float*)d_in[16]; a.bo2 = (const float*)d_in[17];
  a.Wt1 = (const float*)d_in[18]; a.bt1 = (const float*)d_in[19];
  a.Wt2 = (const float*)d_in[20]; a.bt2 = (const float*)d_in[21];
  a.Wt3 = (const float*)d_in[22]; a.bt3 = (const float*)d_in[23];
  a.out = (float*)d_out;
  a.wsw = (half_t*)d_ws;
  a.dts = (float*)((char*)d_ws + DTS_BYTE_OFF);

  swz_kernel<<<dim3(504), dim3(256), 0, stream>>>(a);
  dts_kernel<<<dim3(1), dim3(256), 0, stream>>>(a);
  odegru_kernel<<<dim3(16), dim3(1024), 0, stream>>>(a);
}